// Round 10
// baseline (2082.144 us; speedup 1.0000x reference)
//
#include <hip/hip_runtime.h>
#include <cstdint>

typedef unsigned short u16;
typedef unsigned int u32;
typedef __attribute__((ext_vector_type(8))) short vs8;   // 8 x bf16 MFMA frag
typedef __attribute__((ext_vector_type(4))) short vs4;
typedef __attribute__((ext_vector_type(4))) float vf4;
typedef __attribute__((ext_vector_type(4))) float f32x4;

#define NLAYER 4
#define SEQ 512
#define BATCH 16
#define DM 1024
#define NTOK 8192
#define DOUT 10000
#define DOUTP 10240

static __device__ __forceinline__ u16 f2bf(float f) {
    u32 u = __float_as_uint(f);
    return (u16)((u + 0x7FFFu + ((u >> 16) & 1u)) >> 16);  // RNE
}
static __device__ __forceinline__ float bf2f(u16 h) { return __uint_as_float((u32)h << 16); }

static __device__ __forceinline__ void gload16(const void* g, void* l) {
    __builtin_amdgcn_global_load_lds(
        (const __attribute__((address_space(1))) u32*)(uintptr_t)g,
        (__attribute__((address_space(3))) u32*)(u32)(uintptr_t)l, 16, 0, 0);
}

// ---------------------------------------------------------------------------
// Ring GEMM: C[M,N] = A[M,K] @ W[N,K]^T (+ bias).
// 128x256 tile, BK=32, 512 thr = 8 waves (2M x 4N), wave-tile 64x64 (acc=64).
// 3-ring LDS (72KB) -> with launch_bounds(512,4) (regs<=128): 2 blocks/CU.
// One barrier per K-tile: {8 ds_read | stage tt+2 -> ring+2 | lgkm(0) |
//   16 MFMA | vmcnt(3) | barrier}. Staging never touches a ring until the
//   barrier following its reads. NSP: split-K (f32 partials, no bias).
// ---------------------------------------------------------------------------
template <int NSP, bool RELU, bool OUTBF, bool TRV = false>
__global__ __launch_bounds__(512, 4) void gemm1p(const u16* __restrict__ A, const u16* __restrict__ Bw,
                                                 const float* __restrict__ bias, void* __restrict__ Cv,
                                                 int N, int K, int nMt, int nNt)
{
    __shared__ __align__(16) u16 lds[3 * 128 * 32 + 3 * 256 * 32];   // 72KB
    u16* As = lds;
    u16* Bs = lds + 3 * 128 * 32;

    const int t = threadIdx.x;
    const int wid = t >> 6, lane = t & 63;
    const int lr = lane & 15, lg = lane >> 4;
    const int wr = wid >> 2, wc = wid & 3;
    const int wrb = wr * 64, wcb = wc * 64;
    const int slot8 = (lg ^ ((lr >> 1) & 3)) * 8;

    // --- XCD-bijective remap + GN=8 grouped raster over (nMt*NSP) x nNt ---
    const int nMtE = nMt * NSP;
    const int nwg = nMtE * nNt;
    const int orig = blockIdx.x;
    const int q8 = nwg >> 3, r8 = nwg & 7;
    const int xcd = orig & 7, idx = orig >> 3;
    const int wg = ((xcd < r8) ? xcd * (q8 + 1) : r8 * (q8 + 1) + (xcd - r8) * q8) + idx;
    const int GN = 8;
    const int gsz = GN * nMtE;
    const int grp = wg / gsz;
    const int rem = wg - grp * gsz;
    const int gw = min(GN, nNt - grp * GN);
    const int mtE = rem / gw;
    const int nt = grp * GN + (rem - mtE * gw);
    const int spl = mtE / nMt;
    const int mt = mtE - spl * nMt;
    const size_t m0 = (size_t)mt * 128;
    const size_t n0 = (size_t)nt * 256;

    const int KS = K / NSP;          // K per block
    const int NT = KS >> 5;          // K-tiles
    const int k0 = spl * KS;

    // staging: issue covers 16 rows x 64B; lane -> row +lane/4, chunk (lane&3)^swz
    const int srow = wid * 16 + (lane >> 2);
    const int scg = (lane & 3) ^ ((lane >> 3) & 3);
    const u16* gA = A + (m0 + srow) * (size_t)K + k0 + scg * 8;
    const u16* gB = Bw + (n0 + srow) * (size_t)K + k0 + scg * 8;
    u16* dA = &As[(wid * 16) * 32];
    u16* dB = &Bs[(wid * 16) * 32];
    const u16* rdA = &As[(wrb + lr) * 32 + slot8];
    const u16* rdB = &Bs[(wcb + lr) * 32 + slot8];

    auto stage = [&](int ring, int kt) {
        gload16(gA + kt, dA + ring * 4096);
        gload16(gB + kt, dB + ring * 8192);
        gload16(gB + (size_t)128 * K + kt, dB + ring * 8192 + 4096);
    };

    f32x4 acc[4][4];
#pragma unroll
    for (int i = 0; i < 4; ++i)
#pragma unroll
        for (int j = 0; j < 4; ++j) acc[i][j] = (f32x4){0.f, 0.f, 0.f, 0.f};

    // prologue: tiles 0,1 -> rings 0,1
    stage(0, 0);
    stage(1, (NT > 1 ? 32 : 0));
    asm volatile("s_waitcnt vmcnt(3)" ::: "memory");
    __builtin_amdgcn_s_barrier();

    int ring = 0;
    for (int tt = 0; tt < NT; ++tt) {
        int ring2 = ring + 2; if (ring2 >= 3) ring2 -= 3;
        vs8 af[4], bf[4];
#pragma unroll
        for (int j = 0; j < 4; ++j) bf[j] = *(const vs8*)(rdB + ring * 8192 + j * 512);
#pragma unroll
        for (int i = 0; i < 4; ++i) af[i] = *(const vs8*)(rdA + ring * 4096 + i * 512);
        const int ktn2 = min(tt + 2, NT - 1) << 5;
        stage(ring2, ktn2);
        asm volatile("s_waitcnt lgkmcnt(0)" ::: "memory");
        __builtin_amdgcn_sched_barrier(0);
        __builtin_amdgcn_s_setprio(1);
#pragma unroll
        for (int i = 0; i < 4; ++i)
#pragma unroll
            for (int j = 0; j < 4; ++j) {
                if constexpr (TRV)
                    acc[i][j] = __builtin_amdgcn_mfma_f32_16x16x32_bf16(af[i], bf[j], acc[i][j], 0, 0, 0);
                else
                    acc[i][j] = __builtin_amdgcn_mfma_f32_16x16x32_bf16(bf[j], af[i], acc[i][j], 0, 0, 0);
            }
        __builtin_amdgcn_s_setprio(0);
        asm volatile("s_waitcnt vmcnt(3)" ::: "memory");
        __builtin_amdgcn_s_barrier();
        ++ring; if (ring == 3) ring = 0;
    }

    asm volatile("s_waitcnt vmcnt(0)" ::: "memory");  // drain clamped tail loads

    if constexpr (TRV) {
        // un-swapped D: lane holds 4 consecutive m-rows (lg*4+r), col fixed (lr).
        // store into V^T layout vt[(b*16 + h)*64 + d][s], s = m&511.
#pragma unroll
        for (int i = 0; i < 4; ++i) {
            const int cm0 = (int)m0 + wrb + 16 * i + lg * 4;
            const int b_ = cm0 >> 9, s_ = cm0 & 511;
#pragma unroll
            for (int j = 0; j < 4; ++j) {
                const int cn = (int)n0 + wcb + 16 * j + lr;   // = h*64 + d
                const float bval = bias[cn];
                vs4 o;
#pragma unroll
                for (int r = 0; r < 4; ++r) o[r] = (short)f2bf(acc[i][j][r] + bval);
                u16* dst = (u16*)Cv + (((size_t)(b_ * 16 + (cn >> 6))) * 64 + (cn & 63)) * 512 + s_;
                *(vs4*)dst = o;
            }
        }
    } else if constexpr (OUTBF) {
        // swapped D: lane holds row cm (lr) x 4 consecutive cols (lg*4+r)
#pragma unroll
        for (int i = 0; i < 4; ++i) {
            const size_t cm = m0 + wrb + 16 * i + lr;
#pragma unroll
            for (int j = 0; j < 4; ++j) {
                const size_t cn = n0 + wcb + 16 * j + lg * 4;
                const vf4 bv4 = *(const vf4*)&bias[cn];
                f32x4 v = acc[i][j];
                vs4 o;
#pragma unroll
                for (int r = 0; r < 4; ++r) {
                    float x = v[r] + bv4[r];
                    if (RELU) x = fmaxf(x, 0.f);
                    o[r] = (short)f2bf(x);
                }
                *(vs4*)&((u16*)Cv)[cm * (size_t)N + cn] = o;
            }
        }
    } else {
        // f32 partial (split-K): no bias
        const size_t partOff = (size_t)spl * ((size_t)nMt * 128) * (size_t)N;
#pragma unroll
        for (int i = 0; i < 4; ++i) {
            const size_t cm = m0 + wrb + 16 * i + lr;
#pragma unroll
            for (int j = 0; j < 4; ++j) {
                const size_t cn = n0 + wcb + 16 * j + lg * 4;
                *(vf4*)&((float*)Cv)[partOff + cm * (size_t)N + cn] = acc[i][j];
            }
        }
    }
}

// ---------------------------------------------------------------------------
// Attention: swapped QK^T => packed vf4 S-writes, vf4 softmax, vs4 P-writes.
// S: f32 [32][520]; P aliased bf16 stride 1040.
// ---------------------------------------------------------------------------
__global__ __launch_bounds__(256) void attn_k(const u16* __restrict__ qb, const u16* __restrict__ kb,
                                              const u16* __restrict__ vtb, u16* __restrict__ ob, int ldq)
{
    __shared__ __align__(16) float SlF[32 * 520];   // 66.5 KB
    const int t = threadIdx.x;
    const int wid = t >> 6, lane = t & 63;
    const int lr = lane & 15, lg = lane >> 4;
    const int bh = blockIdx.x >> 4, qt = blockIdx.x & 15;
    const int b = bh >> 4, h = bh & 15;
    const int q0 = qt * 32;

    vs8 aq[2][2];
#pragma unroll
    for (int i2 = 0; i2 < 2; ++i2)
#pragma unroll
        for (int kk = 0; kk < 2; ++kk)
            aq[i2][kk] = *(const vs8*)(qb + ((size_t)(b * 512 + q0 + 16 * i2 + lr)) * ldq + h * 64 + kk * 32 + lg * 8);

    f32x4 sa[2][8];
#pragma unroll
    for (int i2 = 0; i2 < 2; ++i2)
#pragma unroll
        for (int j = 0; j < 8; ++j) sa[i2][j] = (f32x4){0.f, 0.f, 0.f, 0.f};

#pragma unroll
    for (int j = 0; j < 8; ++j) {
        const int col = 128 * wid + 16 * j + lr;
#pragma unroll
        for (int kk = 0; kk < 2; ++kk) {
            vs8 bk = *(const vs8*)(kb + ((size_t)(b * 512 + col)) * ldq + h * 64 + kk * 32 + lg * 8);
#pragma unroll
            for (int i2 = 0; i2 < 2; ++i2)
                sa[i2][j] = __builtin_amdgcn_mfma_f32_16x16x32_bf16(bk, aq[i2][kk], sa[i2][j], 0, 0, 0);
        }
    }
#pragma unroll
    for (int i2 = 0; i2 < 2; ++i2)
#pragma unroll
        for (int j = 0; j < 8; ++j) {
            vf4 w;
#pragma unroll
            for (int r = 0; r < 4; ++r) w[r] = sa[i2][j][r] * 0.125f;
            *(vf4*)&SlF[(16 * i2 + lr) * 520 + 128 * wid + 16 * j + 4 * lg] = w;
        }
    __syncthreads();

    {
        const int row = t >> 3, seg = t & 7;
        const float* Sr = &SlF[row * 520 + seg * 64];
        float v[64];
        float m = -3.0e38f;
#pragma unroll
        for (int c = 0; c < 16; ++c) {
            const int cc = (c + row + seg) & 15;
            const vf4 w = *(const vf4*)&Sr[cc * 4];
#pragma unroll
            for (int e = 0; e < 4; ++e) { v[c * 4 + e] = w[e]; m = fmaxf(m, w[e]); }
        }
        m = fmaxf(m, __shfl_xor(m, 1));
        m = fmaxf(m, __shfl_xor(m, 2));
        m = fmaxf(m, __shfl_xor(m, 4));
        float s = 0.f;
#pragma unroll
        for (int i = 0; i < 64; ++i) { v[i] = __expf(v[i] - m); s += v[i]; }
        s += __shfl_xor(s, 1);
        s += __shfl_xor(s, 2);
        s += __shfl_xor(s, 4);
        const float inv = 1.f / s;
        u16* P16 = (u16*)SlF;
#pragma unroll
        for (int c = 0; c < 16; ++c) {
            const int cc = (c + row + seg) & 15;
            vs4 o;
#pragma unroll
            for (int e = 0; e < 4; ++e) o[e] = (short)f2bf(v[c * 4 + e] * inv);
            *(vs4*)&P16[row * 1040 + seg * 64 + cc * 4] = o;
        }
    }
    __syncthreads();

    const int rt = wid >> 1, ct0 = (wid & 1) * 2;
    f32x4 oa[2];
    oa[0] = (f32x4){0.f, 0.f, 0.f, 0.f};
    oa[1] = (f32x4){0.f, 0.f, 0.f, 0.f};
    const u16* P16 = (const u16*)SlF;
#pragma unroll
    for (int kt = 0; kt < 16; ++kt) {
        vs8 pa = *(const vs8*)&P16[(16 * rt + lr) * 1040 + kt * 32 + lg * 8];
#pragma unroll
        for (int c = 0; c < 2; ++c) {
            const int col = (ct0 + c) * 16 + lr;
            vs8 bv = *(const vs8*)(vtb + ((size_t)bh * 64 + col) * 512 + kt * 32 + lg * 8);
            oa[c] = __builtin_amdgcn_mfma_f32_16x16x32_bf16(bv, pa, oa[c], 0, 0, 0);
        }
    }
#pragma unroll
    for (int c = 0; c < 2; ++c) {
        const int qq = q0 + 16 * rt + lr;
        const int d0c = h * 64 + (ct0 + c) * 16 + lg * 4;
        vs4 o;
#pragma unroll
        for (int r = 0; r < 4; ++r) o[r] = (short)f2bf(oa[c][r]);
        *(vs4*)&ob[((size_t)b * 512 + qq) * 1024 + d0c] = o;
    }
}

// ---------------------------------------------------------------------------
// Embed: enc_b = bf16(LN0(x[s,b]*keep) + posi[s])
// ---------------------------------------------------------------------------
__global__ __launch_bounds__(256) void embed_k(const float* __restrict__ x, const float* __restrict__ rnd,
                                               const float* __restrict__ posi, const float* __restrict__ w,
                                               const float* __restrict__ bb, u16* __restrict__ outb)
{
    const int tok = blockIdx.x;
    const int b = tok >> 9, s = tok & 511;
    const int t = threadIdx.x;
    const float keep = rnd[tok] > 0.15f ? 1.f : 0.f;
    vf4 xv = ((const vf4*)(x + ((size_t)s * 16 + b) * 1024))[t];
    xv *= keep;
    float s1 = xv[0] + xv[1] + xv[2] + xv[3];
    float s2 = xv[0] * xv[0] + xv[1] * xv[1] + xv[2] * xv[2] + xv[3] * xv[3];
#pragma unroll
    for (int mk = 1; mk < 64; mk <<= 1) { s1 += __shfl_xor(s1, mk); s2 += __shfl_xor(s2, mk); }
    __shared__ float red[8];
    if ((t & 63) == 0) { red[t >> 6] = s1; red[4 + (t >> 6)] = s2; }
    __syncthreads();
    s1 = red[0] + red[1] + red[2] + red[3];
    s2 = red[4] + red[5] + red[6] + red[7];
    const float mu = s1 * (1.f / 1024.f);
    const float var = s2 * (1.f / 1024.f) - mu * mu;
    const float rs = rsqrtf(var + 1e-5f);
    vf4 wv = ((const vf4*)w)[t];
    vf4 bv = ((const vf4*)bb)[t];
    vf4 pv = ((const vf4*)(posi + (size_t)s * 1024))[t];
    vs4 yb;
#pragma unroll
    for (int c = 0; c < 4; ++c)
        yb[c] = (short)f2bf((xv[c] - mu) * rs * wv[c] + bv[c] + pv[c]);
    *(vs4*)(outb + (size_t)tok * 1024 + t * 4) = yb;
}

// ---------------------------------------------------------------------------
// add + LN (bf16 x + bf16 resid)
// ---------------------------------------------------------------------------
__global__ __launch_bounds__(256) void add_ln_k(const u16* x, const u16* resid,
                                                const float* __restrict__ w, const float* __restrict__ bb,
                                                u16* out)
{
    const size_t row = blockIdx.x;
    const int t = threadIdx.x;
    const vs4 xv4 = *(const vs4*)(x + row * 1024 + t * 4);
    const vs4 rv4 = *(const vs4*)(resid + row * 1024 + t * 4);
    float xv[4];
#pragma unroll
    for (int c = 0; c < 4; ++c) xv[c] = bf2f((u16)xv4[c]) + bf2f((u16)rv4[c]);
    float s1 = xv[0] + xv[1] + xv[2] + xv[3];
    float s2 = xv[0] * xv[0] + xv[1] * xv[1] + xv[2] * xv[2] + xv[3] * xv[3];
#pragma unroll
    for (int mk = 1; mk < 64; mk <<= 1) { s1 += __shfl_xor(s1, mk); s2 += __shfl_xor(s2, mk); }
    __shared__ float red[8];
    if ((t & 63) == 0) { red[t >> 6] = s1; red[4 + (t >> 6)] = s2; }
    __syncthreads();
    s1 = red[0] + red[1] + red[2] + red[3];
    s2 = red[4] + red[5] + red[6] + red[7];
    const float mu = s1 * (1.f / 1024.f);
    const float var = s2 * (1.f / 1024.f) - mu * mu;
    const float rs = rsqrtf(var + 1e-5f);
    const vf4 wv = ((const vf4*)w)[t];
    const vf4 bv = ((const vf4*)bb)[t];
    vs4 yb;
#pragma unroll
    for (int c = 0; c < 4; ++c)
        yb[c] = (short)f2bf((xv[c] - mu) * rs * wv[c] + bv[c]);
    *(vs4*)(out + row * 1024 + t * 4) = yb;
}

// ---------------------------------------------------------------------------
// split-K reduce + gemm-bias + residual + LN (f32 p0 + f32 p1 + gbias + bf16 resid)
// ---------------------------------------------------------------------------
__global__ __launch_bounds__(256) void add2_ln_k(const float* __restrict__ p0, const float* __restrict__ p1,
                                                 const float* __restrict__ gb, const u16* resid,
                                                 const float* __restrict__ w, const float* __restrict__ bb,
                                                 u16* out)
{
    const size_t row = blockIdx.x;
    const int t = threadIdx.x;
    const vf4 a0 = ((const vf4*)(p0 + row * 1024))[t];
    const vf4 a1 = ((const vf4*)(p1 + row * 1024))[t];
    const vf4 g = ((const vf4*)gb)[t];
    const vs4 rv4 = *(const vs4*)(resid + row * 1024 + t * 4);
    float xv[4];
#pragma unroll
    for (int c = 0; c < 4; ++c) xv[c] = a0[c] + a1[c] + g[c] + bf2f((u16)rv4[c]);
    float s1 = xv[0] + xv[1] + xv[2] + xv[3];
    float s2 = xv[0] * xv[0] + xv[1] * xv[1] + xv[2] * xv[2] + xv[3] * xv[3];
#pragma unroll
    for (int mk = 1; mk < 64; mk <<= 1) { s1 += __shfl_xor(s1, mk); s2 += __shfl_xor(s2, mk); }
    __shared__ float red[8];
    if ((t & 63) == 0) { red[t >> 6] = s1; red[4 + (t >> 6)] = s2; }
    __syncthreads();
    s1 = red[0] + red[1] + red[2] + red[3];
    s2 = red[4] + red[5] + red[6] + red[7];
    const float mu = s1 * (1.f / 1024.f);
    const float var = s2 * (1.f / 1024.f) - mu * mu;
    const float rs = rsqrtf(var + 1e-5f);
    const vf4 wv = ((const vf4*)w)[t];
    const vf4 bv = ((const vf4*)bb)[t];
    vs4 yb;
#pragma unroll
    for (int c = 0; c < 4; ++c)
        yb[c] = (short)f2bf((xv[c] - mu) * rs * wv[c] + bv[c]);
    *(vs4*)(out + row * 1024 + t * 4) = yb;
}

// ---------------------------------------------------------------------------
// log_softmax: vs4 NT loads, vf4 NT stores, [b,s]->[s,b] transpose
// ---------------------------------------------------------------------------
__global__ __launch_bounds__(256) void logsm_k(const u16* __restrict__ lgts, float* __restrict__ out)
{
    const int tok = blockIdx.x;
    const int b = tok >> 9, s = tok & 511;
    const int t = threadIdx.x;
    const vs4* row4 = (const vs4*)(lgts + (size_t)tok * DOUTP);
    float v[40];
    float m = -3.0e38f;
#pragma unroll
    for (int i = 0; i < 10; ++i) {
        const int g = t + 256 * i;
        const vs4 x4 = __builtin_nontemporal_load(row4 + g);
#pragma unroll
        for (int e = 0; e < 4; ++e) {
            const float f = (g < 2500) ? bf2f((u16)x4[e]) : -3.0e38f;
            v[i * 4 + e] = f;
            m = fmaxf(m, f);
        }
    }
#pragma unroll
    for (int mk = 1; mk < 64; mk <<= 1) m = fmaxf(m, __shfl_xor(m, mk));
    __shared__ float red[8];
    if ((t & 63) == 0) red[t >> 6] = m;
    __syncthreads();
    m = fmaxf(fmaxf(red[0], red[1]), fmaxf(red[2], red[3]));
    float sum = 0.f;
#pragma unroll
    for (int i = 0; i < 40; ++i) { v[i] = __expf(v[i] - m); sum += v[i]; }
#pragma unroll
    for (int mk = 1; mk < 64; mk <<= 1) sum += __shfl_xor(sum, mk);
    if ((t & 63) == 0) red[4 + (t >> 6)] = sum;
    __syncthreads();
    sum = red[4] + red[5] + red[6] + red[7];
    const float ls = m + __logf(sum);
    const float adj = m - ls;
    vf4* orow = (vf4*)(out + ((size_t)s * 16 + b) * DOUT);
#pragma unroll
    for (int i = 0; i < 10; ++i) {
        const int g = t + 256 * i;
        if (g < 2500) {
            vf4 o;
#pragma unroll
            for (int e = 0; e < 4; ++e) o[e] = __logf(v[i * 4 + e]) + adj;
            __builtin_nontemporal_store(o, orow + g);
        }
    }
}

// ---------------------------------------------------------------------------
// One-shot weight/bias prep
// ---------------------------------------------------------------------------
__global__ void prep_k(const float* __restrict__ Wq, const float* __restrict__ Wk,
                       const float* __restrict__ Wv, const float* __restrict__ Wfc,
                       const float* __restrict__ W1, const float* __restrict__ W2,
                       const float* __restrict__ Wo, const float* __restrict__ bq,
                       const float* __restrict__ bk, const float* __restrict__ bo,
                       u16* __restrict__ Wqk_b, u16* __restrict__ Wv_b, u16* __restrict__ Wfc_b,
                       u16* __restrict__ W1_b, u16* __restrict__ W2_b, u16* __restrict__ Wo_b,
                       float* __restrict__ bqk_p, float* __restrict__ bo_p)
{
    const int i = blockIdx.x * 256 + threadIdx.x;
    auto cvt = [](vf4 v) {
        vs4 o;
#pragma unroll
        for (int c = 0; c < 4; ++c) o[c] = (short)f2bf(v[c]);
        return o;
    };
    if (i < 1048576) {                 // Wq -> Wqk[l][0:1024]
        const int l = i >> 18, r = i & 262143;
        ((vs4*)Wqk_b)[(size_t)l * 524288 + r] = cvt(((const vf4*)Wq)[i]);
    } else if (i < 2097152) {          // Wk -> Wqk[l][1024:2048]
        const int ii = i - 1048576;
        const int l = ii >> 18, r = ii & 262143;
        ((vs4*)Wqk_b)[(size_t)l * 524288 + 262144 + r] = cvt(((const vf4*)Wk)[ii]);
    } else if (i < 3145728) {
        const int ii = i - 2097152;
        ((vs4*)Wv_b)[ii] = cvt(((const vf4*)Wv)[ii]);
    } else if (i < 4194304) {
        const int ii = i - 3145728;
        ((vs4*)Wfc_b)[ii] = cvt(((const vf4*)Wfc)[ii]);
    } else if (i < 8388608) {
        const int ii = i - 4194304;
        ((vs4*)W1_b)[ii] = cvt(((const vf4*)W1)[ii]);
    } else if (i < 12582912) {
        const int ii = i - 8388608;
        ((vs4*)W2_b)[ii] = cvt(((const vf4*)W2)[ii]);
    } else if (i < 15204352) {         // Wo padded to DOUTP rows
        const int ii = i - 12582912;
        const size_t e = (size_t)ii * 4;
        const int r = (int)(e >> 10);
        vs4 o;
        if (r < DOUT) o = cvt(*(const vf4*)(Wo + (size_t)r * 1024 + (e & 1023)));
        else { o[0] = o[1] = o[2] = o[3] = 0; }
        *(vs4*)(Wo_b + e) = o;
    } else {
        const int ii = i - 15204352;   // < 4608
        if (ii < 2048) {
            const int f = ii * 4, l = f >> 11, c = f & 2047;
            vf4 v = (c < 1024) ? *(const vf4*)&bq[l * 1024 + c]
                               : *(const vf4*)&bk[l * 1024 + c - 1024];
            *(vf4*)&bqk_p[f] = v;
        } else {
            const int f = (ii - 2048) * 4;
            vf4 o;
#pragma unroll
            for (int e = 0; e < 4; ++e) o[e] = (f + e < DOUT) ? bo[f + e] : 0.f;
            *(vf4*)&bo_p[f] = o;
        }
    }
}

// ---------------------------------------------------------------------------
extern "C" void kernel_launch(void* const* d_in, const int* in_sizes, int n_in,
                              void* d_out, int out_size, void* d_ws, size_t ws_size,
                              hipStream_t stream)
{
    (void)in_sizes; (void)n_in; (void)out_size; (void)ws_size;
    const float* x     = (const float*)d_in[0];
    const float* rnd   = (const float*)d_in[1];
    const float* posi  = (const float*)d_in[2];
    const float* ln0_w = (const float*)d_in[3];
    const float* ln0_b = (const float*)d_in[4];
    const float* Wq    = (const float*)d_in[5];
    const float* bq    = (const float*)d_in[6];
    const float* Wk    = (const float*)d_in[7];
    const float* bk    = (const float*)d_in[8];
    const float* Wv    = (const float*)d_in[9];
    const float* bv    = (const float*)d_in[10];
    const float* Wfc   = (const float*)d_in[11];
    const float* bfc   = (const float*)d_in[12];
    const float* ln1_w = (const float*)d_in[13];
    const float* ln1_b = (const float*)d_in[14];
    const float* W1    = (const float*)d_in[15];
    const float* b1    = (const float*)d_in[16];
    const float* W2    = (const float*)d_in[17];
    const float* b2    = (const float*)d_in[18];
    const float* ln2_w = (const float*)d_in[19];
    const float* ln2_b = (const float*)d_in[20];
    const float* Wo    = (const float*)d_in[21];
    const float* bo    = (const float*)d_in[22];

    char* p = (char*)d_ws;
    size_t off = 0;
    auto take = [&](size_t bytes) {
        char* r = p + off;
        off += (bytes + 255) & ~(size_t)255;
        return r;
    };
    u16*   Wqk_b  = (u16*)take((size_t)NLAYER * 2048 * 1024 * 2);
    u16*   Wv_b   = (u16*)take((size_t)NLAYER * 1024 * 1024 * 2);
    u16*   Wfc_b  = (u16*)take((size_t)NLAYER * 1024 * 1024 * 2);
    u16*   W1_b   = (u16*)take((size_t)NLAYER * 4096 * 1024 * 2);
    u16*   W2_b   = (u16*)take((size_t)NLAYER * 4096 * 1024 * 2);
    u16*   Wo_b   = (u16*)take((size_t)DOUTP * DM * 2);
    float* bqk_p  = (float*)take(NLAYER * 2048 * 4);
    float* bo_p   = (float*)take(DOUTP * 4);
    u16*   enc_b  = (u16*)take((size_t)NTOK * DM * 2);
    char*  pool   = take((size_t)NTOK * DOUTP * 2);   // 167.8 MB
    // lifetimes:
    //  attn_b [0,16.8M) ; qkv [16.8,50.3M) ; vt [50.3,67.1M)
    //  fc partials p0 [16.8,50.3M), p1 [50.3,83.9M)  (qkv,vt dead; attn_b live)
    //  ff [0,67.1M)  (attn_b, partials dead after add2_ln)
    //  W2 partials q0 [67.1,100.7M), q1 [100.7,134.2M)  (ff live)
    //  lgt [0,167.8M)
    u16*   attn_b = (u16*)(pool);
    u16*   qkv_b  = (u16*)(pool + 16777216);
    u16*   vt_b   = (u16*)(pool + 50331648);
    float* fcp0   = (float*)(pool + 16777216);
    float* fcp1   = (float*)(pool + 50331648);
    u16*   ff_b   = (u16*)(pool);
    float* w2p0   = (float*)(pool + 67108864);
    float* w2p1   = (float*)(pool + 100663296);
    u16*   lgt_b  = (u16*)(pool);

    const dim3 blk(256);
    prep_k<<<59410, blk, 0, stream>>>(Wq, Wk, Wv, Wfc, W1, W2, Wo, bq, bk, bo,
                                      Wqk_b, Wv_b, Wfc_b, W1_b, W2_b, Wo_b, bqk_p, bo_p);

    embed_k<<<NTOK, blk, 0, stream>>>(x, rnd, posi, ln0_w, ln0_b, enc_b);

    for (int l = 0; l < NLAYER; ++l) {
        // QK: [8192,2048] = enc @ Wqk^T   (512 blocks, 2/CU)
        gemm1p<1, false, true><<<512, 512, 0, stream>>>(enc_b, Wqk_b + (size_t)l * 2097152,
                                                        bqk_p + l * 2048, qkv_b, 2048, 1024, 64, 8);
        // V -> V^T layout (TRV)
        gemm1p<1, false, true, true><<<256, 512, 0, stream>>>(enc_b, Wv_b + (size_t)l * 1048576,
                                                              bv + l * 1024, vt_b, 1024, 1024, 64, 4);
        attn_k<<<4096, blk, 0, stream>>>(qkv_b, qkv_b + 1024, vt_b, attn_b, 2048);
        // fc: split-K2 -> f32 partials (512 blocks, 2/CU)
        gemm1p<2, false, false><<<512, 512, 0, stream>>>(attn_b, Wfc_b + (size_t)l * 1048576,
                                                         nullptr, fcp0, 1024, 1024, 64, 4);
        add2_ln_k<<<NTOK, blk, 0, stream>>>(fcp0, fcp1, bfc + l * 1024, enc_b,
                                            ln1_w + l * 1024, ln1_b + l * 1024, enc_b);
        // W1 (1024 blocks, 2/CU)
        gemm1p<1, true, true><<<1024, 512, 0, stream>>>(enc_b, W1_b + (size_t)l * 4194304,
                                                        b1 + l * 4096, ff_b, 4096, 1024, 64, 16);
        // W2: split-K2 (512 blocks, 2/CU)
        gemm1p<2, false, false><<<512, 512, 0, stream>>>(ff_b, W2_b + (size_t)l * 4194304,
                                                         nullptr, w2p0, 1024, 4096, 64, 4);
        add2_ln_k<<<NTOK, blk, 0, stream>>>(w2p0, w2p1, b2 + l * 1024, enc_b,
                                            ln2_w + l * 1024, ln2_b + l * 1024, enc_b);
    }

    gemm1p<1, false, true><<<2560, 512, 0, stream>>>(enc_b, Wo_b, bo_p, lgt_b, DOUTP, 1024, 64, 40);
    logsm_k<<<NTOK, blk, 0, stream>>>(lgt_b, (float*)d_out);
}

// Round 11
// 1889.214 us; speedup vs baseline: 1.1021x; 1.1021x over previous
//
#include <hip/hip_runtime.h>
#include <cstdint>

typedef unsigned short u16;
typedef unsigned int u32;
typedef __attribute__((ext_vector_type(8))) short vs8;   // 8 x bf16 MFMA frag
typedef __attribute__((ext_vector_type(4))) short vs4;
typedef __attribute__((ext_vector_type(4))) float vf4;
typedef __attribute__((ext_vector_type(4))) float f32x4;

#define NLAYER 4
#define SEQ 512
#define BATCH 16
#define DM 1024
#define NTOK 8192
#define DOUT 10000
#define DOUTP 10240

static __device__ __forceinline__ u16 f2bf(float f) {
    u32 u = __float_as_uint(f);
    return (u16)((u + 0x7FFFu + ((u >> 16) & 1u)) >> 16);  // RNE
}
static __device__ __forceinline__ float bf2f(u16 h) { return __uint_as_float((u32)h << 16); }

static __device__ __forceinline__ void gload16(const void* g, void* l) {
    __builtin_amdgcn_global_load_lds(
        (const __attribute__((address_space(1))) u32*)(uintptr_t)g,
        (__attribute__((address_space(3))) u32*)(u32)(uintptr_t)l, 16, 0, 0);
}

// ---------------------------------------------------------------------------
// 2-phase GEMM: C[M,N] = A[M,K] @ W[N,K]^T + bias.  (R8 configuration — best)
// BM x 256 tile, BK=64 (2 k-halves), 512 thr = 8 waves (2M x 4N).
// Default: swapped-operand MFMA => lane holds 4 consecutive N-cols (packed
//   row-major C stores).
// TRV: un-swapped MFMA => lane holds 4 consecutive M-rows => packed stores
//   into V^T layout vt[(b*16+h)*64+d][s] (eliminates separate transpose).
// ---------------------------------------------------------------------------
template <int BM, bool RELU, bool OUTBF, bool TRV = false>
__global__ __launch_bounds__(512, 1) void gemm2p(const u16* __restrict__ A, const u16* __restrict__ Bw,
                                                 const float* __restrict__ bias, void* __restrict__ Cv,
                                                 int N, int K, int nMt, int nNt)
{
    constexpr int LA = BM / 128;
    constexpr int LB = 2;
    constexpr int WCNT = 2 * (LA + LB);    // 8 (BM=256) / 6 (BM=128)
    constexpr int MR = BM / 32;

    __shared__ __align__(16) u16 lds[2 * 2 * BM * 32 + 2 * 2 * 256 * 32];
    u16* As = lds;
    u16* Bs = lds + 2 * 2 * BM * 32;

    const int t = threadIdx.x;
    const int wid = t >> 6, lane = t & 63;
    const int lr = lane & 15, lg = lane >> 4;
    const int wr = wid >> 2, wc = wid & 3;
    const int wrb = wr * (BM / 2), wcb = wc * 64;
    const int slot8 = (lg ^ ((lr >> 1) & 3)) * 8;

    // --- XCD-bijective remap + GN=8 grouped raster ---
    const int nwg = nMt * nNt;
    const int orig = blockIdx.x;
    const int q8 = nwg >> 3, r8 = nwg & 7;
    const int xcd = orig & 7, idx = orig >> 3;
    const int wg = ((xcd < r8) ? xcd * (q8 + 1) : r8 * (q8 + 1) + (xcd - r8) * q8) + idx;
    const int GN = 8;
    const int gsz = GN * nMt;
    const int grp = wg / gsz;
    const int rem = wg - grp * gsz;
    const int gw = min(GN, nNt - grp * GN);
    const int mt = rem / gw;
    const int nt = grp * GN + (rem - mt * gw);
    const size_t m0 = (size_t)mt * BM;
    const size_t n0 = (size_t)nt * 256;

    const int srow = wid * 16 + (lane >> 2);
    const int scg = (lane & 3) ^ ((lane >> 3) & 3);
    const u16* gA = A + (m0 + srow) * (size_t)K + scg * 8;
    const u16* gB = Bw + (n0 + srow) * (size_t)K + scg * 8;

    auto stageA = [&](int b, int kh, int kt) {
#pragma unroll
        for (int i = 0; i < LA; ++i)
            gload16(gA + (size_t)i * 128 * K + kt + kh * 32,
                    &As[(((b << 1) + kh) * BM + (i * 8 + wid) * 16) * 32]);
    };
    auto stageB = [&](int b, int kh, int kt) {
#pragma unroll
        for (int i = 0; i < LB; ++i)
            gload16(gB + (size_t)i * 128 * K + kt + kh * 32,
                    &Bs[(((b << 1) + kh) * 256 + (i * 8 + wid) * 16) * 32]);
    };
    auto ldA = [&](int i, int kk, int b) -> vs8 {
        return *(const vs8*)&As[(((b << 1) + kk) * BM + wrb + i * 16 + lr) * 32 + slot8];
    };
    auto ldB = [&](int j, int kk, int b) -> vs8 {
        return *(const vs8*)&Bs[(((b << 1) + kk) * 256 + wcb + j * 16 + lr) * 32 + slot8];
    };

    f32x4 acc[MR][4];
#pragma unroll
    for (int i = 0; i < MR; ++i)
#pragma unroll
        for (int j = 0; j < 4; ++j) acc[i][j] = (f32x4){0.f, 0.f, 0.f, 0.f};

    const int NT = K >> 6;

    stageA(0, 0, 0); stageB(0, 0, 0);
    stageA(0, 1, 0); stageB(0, 1, 0);
    stageA(1, 0, 64); stageB(1, 0, 64);
    if constexpr (WCNT == 8) asm volatile("s_waitcnt vmcnt(8)" ::: "memory");
    else                     asm volatile("s_waitcnt vmcnt(6)" ::: "memory");
    __builtin_amdgcn_s_barrier();

    for (int tt = 0; tt < NT; ++tt) {
        const int buf = tt & 1;
        const int ktn = min(tt + 1, NT - 1) << 6;
        const int ktn2 = min(tt + 2, NT - 1) << 6;
        vs8 af[MR], bf[4];

        // ---- ph0: kk=0 ----
#pragma unroll
        for (int j = 0; j < 4; ++j) bf[j] = ldB(j, 0, buf);
#pragma unroll
        for (int i = 0; i < MR; ++i) af[i] = ldA(i, 0, buf);
        stageA(buf ^ 1, 1, ktn);
        stageB(buf ^ 1, 1, ktn);
        __builtin_amdgcn_s_barrier();
        asm volatile("s_waitcnt lgkmcnt(0)" ::: "memory");
        __builtin_amdgcn_sched_barrier(0);
        __builtin_amdgcn_s_setprio(1);
#pragma unroll
        for (int i = 0; i < MR; ++i)
#pragma unroll
            for (int j = 0; j < 4; ++j) {
                if constexpr (TRV)
                    acc[i][j] = __builtin_amdgcn_mfma_f32_16x16x32_bf16(af[i], bf[j], acc[i][j], 0, 0, 0);
                else
                    acc[i][j] = __builtin_amdgcn_mfma_f32_16x16x32_bf16(bf[j], af[i], acc[i][j], 0, 0, 0);
            }
        __builtin_amdgcn_s_setprio(0);
        if constexpr (WCNT == 8) asm volatile("s_waitcnt vmcnt(8)" ::: "memory");
        else                     asm volatile("s_waitcnt vmcnt(6)" ::: "memory");
        __builtin_amdgcn_s_barrier();

        // ---- ph1: kk=1 ----
#pragma unroll
        for (int j = 0; j < 4; ++j) bf[j] = ldB(j, 1, buf);
#pragma unroll
        for (int i = 0; i < MR; ++i) af[i] = ldA(i, 1, buf);
        stageA(buf, 0, ktn2);
        stageB(buf, 0, ktn2);
        __builtin_amdgcn_s_barrier();
        asm volatile("s_waitcnt lgkmcnt(0)" ::: "memory");
        __builtin_amdgcn_sched_barrier(0);
        __builtin_amdgcn_s_setprio(1);
#pragma unroll
        for (int i = 0; i < MR; ++i)
#pragma unroll
            for (int j = 0; j < 4; ++j) {
                if constexpr (TRV)
                    acc[i][j] = __builtin_amdgcn_mfma_f32_16x16x32_bf16(af[i], bf[j], acc[i][j], 0, 0, 0);
                else
                    acc[i][j] = __builtin_amdgcn_mfma_f32_16x16x32_bf16(bf[j], af[i], acc[i][j], 0, 0, 0);
            }
        __builtin_amdgcn_s_setprio(0);
        if constexpr (WCNT == 8) asm volatile("s_waitcnt vmcnt(8)" ::: "memory");
        else                     asm volatile("s_waitcnt vmcnt(6)" ::: "memory");
        __builtin_amdgcn_s_barrier();
    }

    asm volatile("s_waitcnt vmcnt(0)" ::: "memory");

    if constexpr (TRV) {
#pragma unroll
        for (int i = 0; i < MR; ++i) {
            const int cm0 = (int)m0 + wrb + 16 * i + lg * 4;
            const int b_ = cm0 >> 9, s_ = cm0 & 511;
#pragma unroll
            for (int j = 0; j < 4; ++j) {
                const int cn = (int)n0 + wcb + 16 * j + lr;   // = h*64 + d
                const float bval = bias[cn];
                vs4 o;
#pragma unroll
                for (int r = 0; r < 4; ++r) o[r] = (short)f2bf(acc[i][j][r] + bval);
                u16* dst = (u16*)Cv + (((size_t)(b_ * 16 + (cn >> 6))) * 64 + (cn & 63)) * 512 + s_;
                *(vs4*)dst = o;
            }
        }
    } else {
#pragma unroll
        for (int i = 0; i < MR; ++i) {
            const size_t cm = m0 + wrb + 16 * i + lr;
#pragma unroll
            for (int j = 0; j < 4; ++j) {
                const size_t cn = n0 + wcb + 16 * j + lg * 4;
                const vf4 bv4 = *(const vf4*)&bias[cn];
                f32x4 v = acc[i][j];
#pragma unroll
                for (int r = 0; r < 4; ++r) {
                    v[r] += bv4[r];
                    if (RELU) v[r] = fmaxf(v[r], 0.f);
                }
                if (OUTBF) {
                    vs4 o;
#pragma unroll
                    for (int r = 0; r < 4; ++r) o[r] = (short)f2bf(v[r]);
                    *(vs4*)&((u16*)Cv)[cm * (size_t)N + cn] = o;
                } else {
                    *(vf4*)&((float*)Cv)[cm * (size_t)N + cn] = v;
                }
            }
        }
    }
}

// ---------------------------------------------------------------------------
// Attention: swapped QK^T => packed vf4 S-writes, vf4 softmax, vs4 P-writes.
// S: f32 [32][520]; P aliased bf16 stride 1040.
// ---------------------------------------------------------------------------
__global__ __launch_bounds__(256) void attn_k(const u16* __restrict__ qb, const u16* __restrict__ kb,
                                              const u16* __restrict__ vtb, u16* __restrict__ ob, int ldq)
{
    __shared__ __align__(16) float SlF[32 * 520];   // 66.5 KB
    const int t = threadIdx.x;
    const int wid = t >> 6, lane = t & 63;
    const int lr = lane & 15, lg = lane >> 4;
    const int bh = blockIdx.x >> 4, qt = blockIdx.x & 15;
    const int b = bh >> 4, h = bh & 15;
    const int q0 = qt * 32;

    vs8 aq[2][2];
#pragma unroll
    for (int i2 = 0; i2 < 2; ++i2)
#pragma unroll
        for (int kk = 0; kk < 2; ++kk)
            aq[i2][kk] = *(const vs8*)(qb + ((size_t)(b * 512 + q0 + 16 * i2 + lr)) * ldq + h * 64 + kk * 32 + lg * 8);

    f32x4 sa[2][8];
#pragma unroll
    for (int i2 = 0; i2 < 2; ++i2)
#pragma unroll
        for (int j = 0; j < 8; ++j) sa[i2][j] = (f32x4){0.f, 0.f, 0.f, 0.f};

#pragma unroll
    for (int j = 0; j < 8; ++j) {
        const int col = 128 * wid + 16 * j + lr;
#pragma unroll
        for (int kk = 0; kk < 2; ++kk) {
            vs8 bk = *(const vs8*)(kb + ((size_t)(b * 512 + col)) * ldq + h * 64 + kk * 32 + lg * 8);
#pragma unroll
            for (int i2 = 0; i2 < 2; ++i2)
                sa[i2][j] = __builtin_amdgcn_mfma_f32_16x16x32_bf16(bk, aq[i2][kk], sa[i2][j], 0, 0, 0);
        }
    }
#pragma unroll
    for (int i2 = 0; i2 < 2; ++i2)
#pragma unroll
        for (int j = 0; j < 8; ++j) {
            vf4 w;
#pragma unroll
            for (int r = 0; r < 4; ++r) w[r] = sa[i2][j][r] * 0.125f;
            *(vf4*)&SlF[(16 * i2 + lr) * 520 + 128 * wid + 16 * j + 4 * lg] = w;
        }
    __syncthreads();

    {
        const int row = t >> 3, seg = t & 7;
        const float* Sr = &SlF[row * 520 + seg * 64];
        float v[64];
        float m = -3.0e38f;
#pragma unroll
        for (int c = 0; c < 16; ++c) {
            const int cc = (c + row + seg) & 15;
            const vf4 w = *(const vf4*)&Sr[cc * 4];
#pragma unroll
            for (int e = 0; e < 4; ++e) { v[c * 4 + e] = w[e]; m = fmaxf(m, w[e]); }
        }
        m = fmaxf(m, __shfl_xor(m, 1));
        m = fmaxf(m, __shfl_xor(m, 2));
        m = fmaxf(m, __shfl_xor(m, 4));
        float s = 0.f;
#pragma unroll
        for (int i = 0; i < 64; ++i) { v[i] = __expf(v[i] - m); s += v[i]; }
        s += __shfl_xor(s, 1);
        s += __shfl_xor(s, 2);
        s += __shfl_xor(s, 4);
        const float inv = 1.f / s;
        u16* P16 = (u16*)SlF;
#pragma unroll
        for (int c = 0; c < 16; ++c) {
            const int cc = (c + row + seg) & 15;
            vs4 o;
#pragma unroll
            for (int e = 0; e < 4; ++e) o[e] = (short)f2bf(v[c * 4 + e] * inv);
            *(vs4*)&P16[row * 1040 + seg * 64 + cc * 4] = o;
        }
    }
    __syncthreads();

    const int rt = wid >> 1, ct0 = (wid & 1) * 2;
    f32x4 oa[2];
    oa[0] = (f32x4){0.f, 0.f, 0.f, 0.f};
    oa[1] = (f32x4){0.f, 0.f, 0.f, 0.f};
    const u16* P16 = (const u16*)SlF;
#pragma unroll
    for (int kt = 0; kt < 16; ++kt) {
        vs8 pa = *(const vs8*)&P16[(16 * rt + lr) * 1040 + kt * 32 + lg * 8];
#pragma unroll
        for (int c = 0; c < 2; ++c) {
            const int col = (ct0 + c) * 16 + lr;
            vs8 bv = *(const vs8*)(vtb + ((size_t)bh * 64 + col) * 512 + kt * 32 + lg * 8);
            oa[c] = __builtin_amdgcn_mfma_f32_16x16x32_bf16(bv, pa, oa[c], 0, 0, 0);
        }
    }
#pragma unroll
    for (int c = 0; c < 2; ++c) {
        const int qq = q0 + 16 * rt + lr;
        const int d0c = h * 64 + (ct0 + c) * 16 + lg * 4;
        vs4 o;
#pragma unroll
        for (int r = 0; r < 4; ++r) o[r] = (short)f2bf(oa[c][r]);
        *(vs4*)&ob[((size_t)b * 512 + qq) * 1024 + d0c] = o;
    }
}

// ---------------------------------------------------------------------------
// Embed: enc_b = bf16(LN0(x[s,b]*keep) + posi[s])
// ---------------------------------------------------------------------------
__global__ __launch_bounds__(256) void embed_k(const float* __restrict__ x, const float* __restrict__ rnd,
                                               const float* __restrict__ posi, const float* __restrict__ w,
                                               const float* __restrict__ bb, u16* __restrict__ outb)
{
    const int tok = blockIdx.x;
    const int b = tok >> 9, s = tok & 511;
    const int t = threadIdx.x;
    const float keep = rnd[tok] > 0.15f ? 1.f : 0.f;
    vf4 xv = ((const vf4*)(x + ((size_t)s * 16 + b) * 1024))[t];
    xv *= keep;
    float s1 = xv[0] + xv[1] + xv[2] + xv[3];
    float s2 = xv[0] * xv[0] + xv[1] * xv[1] + xv[2] * xv[2] + xv[3] * xv[3];
#pragma unroll
    for (int mk = 1; mk < 64; mk <<= 1) { s1 += __shfl_xor(s1, mk); s2 += __shfl_xor(s2, mk); }
    __shared__ float red[8];
    if ((t & 63) == 0) { red[t >> 6] = s1; red[4 + (t >> 6)] = s2; }
    __syncthreads();
    s1 = red[0] + red[1] + red[2] + red[3];
    s2 = red[4] + red[5] + red[6] + red[7];
    const float mu = s1 * (1.f / 1024.f);
    const float var = s2 * (1.f / 1024.f) - mu * mu;
    const float rs = rsqrtf(var + 1e-5f);
    vf4 wv = ((const vf4*)w)[t];
    vf4 bv = ((const vf4*)bb)[t];
    vf4 pv = ((const vf4*)(posi + (size_t)s * 1024))[t];
    vs4 yb;
#pragma unroll
    for (int c = 0; c < 4; ++c)
        yb[c] = (short)f2bf((xv[c] - mu) * rs * wv[c] + bv[c] + pv[c]);
    *(vs4*)(outb + (size_t)tok * 1024 + t * 4) = yb;
}

// ---------------------------------------------------------------------------
// add + LN, bf16 pipeline
// ---------------------------------------------------------------------------
__global__ __launch_bounds__(256) void add_ln_k(const u16* x, const u16* resid,
                                                const float* __restrict__ w, const float* __restrict__ bb,
                                                u16* out)
{
    const size_t row = blockIdx.x;
    const int t = threadIdx.x;
    const vs4 xv4 = *(const vs4*)(x + row * 1024 + t * 4);
    const vs4 rv4 = *(const vs4*)(resid + row * 1024 + t * 4);
    float xv[4];
#pragma unroll
    for (int c = 0; c < 4; ++c) xv[c] = bf2f((u16)xv4[c]) + bf2f((u16)rv4[c]);
    float s1 = xv[0] + xv[1] + xv[2] + xv[3];
    float s2 = xv[0] * xv[0] + xv[1] * xv[1] + xv[2] * xv[2] + xv[3] * xv[3];
#pragma unroll
    for (int mk = 1; mk < 64; mk <<= 1) { s1 += __shfl_xor(s1, mk); s2 += __shfl_xor(s2, mk); }
    __shared__ float red[8];
    if ((t & 63) == 0) { red[t >> 6] = s1; red[4 + (t >> 6)] = s2; }
    __syncthreads();
    s1 = red[0] + red[1] + red[2] + red[3];
    s2 = red[4] + red[5] + red[6] + red[7];
    const float mu = s1 * (1.f / 1024.f);
    const float var = s2 * (1.f / 1024.f) - mu * mu;
    const float rs = rsqrtf(var + 1e-5f);
    const vf4 wv = ((const vf4*)w)[t];
    const vf4 bv = ((const vf4*)bb)[t];
    vs4 yb;
#pragma unroll
    for (int c = 0; c < 4; ++c)
        yb[c] = (short)f2bf((xv[c] - mu) * rs * wv[c] + bv[c]);
    *(vs4*)(out + row * 1024 + t * 4) = yb;
}

// ---------------------------------------------------------------------------
// log_softmax: vs4 NT loads, vf4 NT stores, [b,s]->[s,b] transpose
// ---------------------------------------------------------------------------
__global__ __launch_bounds__(256) void logsm_k(const u16* __restrict__ lgts, float* __restrict__ out)
{
    const int tok = blockIdx.x;
    const int b = tok >> 9, s = tok & 511;
    const int t = threadIdx.x;
    const vs4* row4 = (const vs4*)(lgts + (size_t)tok * DOUTP);
    float v[40];
    float m = -3.0e38f;
#pragma unroll
    for (int i = 0; i < 10; ++i) {
        const int g = t + 256 * i;
        const vs4 x4 = __builtin_nontemporal_load(row4 + g);
#pragma unroll
        for (int e = 0; e < 4; ++e) {
            const float f = (g < 2500) ? bf2f((u16)x4[e]) : -3.0e38f;
            v[i * 4 + e] = f;
            m = fmaxf(m, f);
        }
    }
#pragma unroll
    for (int mk = 1; mk < 64; mk <<= 1) m = fmaxf(m, __shfl_xor(m, mk));
    __shared__ float red[8];
    if ((t & 63) == 0) red[t >> 6] = m;
    __syncthreads();
    m = fmaxf(fmaxf(red[0], red[1]), fmaxf(red[2], red[3]));
    float sum = 0.f;
#pragma unroll
    for (int i = 0; i < 40; ++i) { v[i] = __expf(v[i] - m); sum += v[i]; }
#pragma unroll
    for (int mk = 1; mk < 64; mk <<= 1) sum += __shfl_xor(sum, mk);
    if ((t & 63) == 0) red[4 + (t >> 6)] = sum;
    __syncthreads();
    sum = red[4] + red[5] + red[6] + red[7];
    const float ls = m + __logf(sum);
    const float adj = m - ls;
    vf4* orow = (vf4*)(out + ((size_t)s * 16 + b) * DOUT);
#pragma unroll
    for (int i = 0; i < 10; ++i) {
        const int g = t + 256 * i;
        if (g < 2500) {
            vf4 o;
#pragma unroll
            for (int e = 0; e < 4; ++e) o[e] = __logf(v[i * 4 + e]) + adj;
            __builtin_nontemporal_store(o, orow + g);
        }
    }
}

// ---------------------------------------------------------------------------
// One-shot weight/bias prep (NT loads: read-once fp32 weights skip L2/L3)
// ---------------------------------------------------------------------------
__global__ void prep_k(const float* __restrict__ Wq, const float* __restrict__ Wk,
                       const float* __restrict__ Wv, const float* __restrict__ Wfc,
                       const float* __restrict__ W1, const float* __restrict__ W2,
                       const float* __restrict__ Wo, const float* __restrict__ bq,
                       const float* __restrict__ bk, const float* __restrict__ bo,
                       u16* __restrict__ Wqk_b, u16* __restrict__ Wv_b, u16* __restrict__ Wfc_b,
                       u16* __restrict__ W1_b, u16* __restrict__ W2_b, u16* __restrict__ Wo_b,
                       float* __restrict__ bqk_p, float* __restrict__ bo_p)
{
    const int i = blockIdx.x * 256 + threadIdx.x;
    auto cvt = [](vf4 v) {
        vs4 o;
#pragma unroll
        for (int c = 0; c < 4; ++c) o[c] = (short)f2bf(v[c]);
        return o;
    };
    if (i < 1048576) {                 // Wq -> Wqk[l][0:1024]
        const int l = i >> 18, r = i & 262143;
        ((vs4*)Wqk_b)[(size_t)l * 524288 + r] = cvt(__builtin_nontemporal_load(((const vf4*)Wq) + i));
    } else if (i < 2097152) {          // Wk -> Wqk[l][1024:2048]
        const int ii = i - 1048576;
        const int l = ii >> 18, r = ii & 262143;
        ((vs4*)Wqk_b)[(size_t)l * 524288 + 262144 + r] = cvt(__builtin_nontemporal_load(((const vf4*)Wk) + ii));
    } else if (i < 3145728) {
        const int ii = i - 2097152;
        ((vs4*)Wv_b)[ii] = cvt(__builtin_nontemporal_load(((const vf4*)Wv) + ii));
    } else if (i < 4194304) {
        const int ii = i - 3145728;
        ((vs4*)Wfc_b)[ii] = cvt(__builtin_nontemporal_load(((const vf4*)Wfc) + ii));
    } else if (i < 8388608) {
        const int ii = i - 4194304;
        ((vs4*)W1_b)[ii] = cvt(__builtin_nontemporal_load(((const vf4*)W1) + ii));
    } else if (i < 12582912) {
        const int ii = i - 8388608;
        ((vs4*)W2_b)[ii] = cvt(__builtin_nontemporal_load(((const vf4*)W2) + ii));
    } else if (i < 15204352) {         // Wo padded to DOUTP rows
        const int ii = i - 12582912;
        const size_t e = (size_t)ii * 4;
        const int r = (int)(e >> 10);
        vs4 o;
        if (r < DOUT) o = cvt(__builtin_nontemporal_load((const vf4*)(Wo + (size_t)r * 1024 + (e & 1023))));
        else { o[0] = o[1] = o[2] = o[3] = 0; }
        *(vs4*)(Wo_b + e) = o;
    } else {
        const int ii = i - 15204352;   // < 4608
        if (ii < 2048) {
            const int f = ii * 4, l = f >> 11, c = f & 2047;
            vf4 v = (c < 1024) ? *(const vf4*)&bq[l * 1024 + c]
                               : *(const vf4*)&bk[l * 1024 + c - 1024];
            *(vf4*)&bqk_p[f] = v;
        } else {
            const int f = (ii - 2048) * 4;
            vf4 o;
#pragma unroll
            for (int e = 0; e < 4; ++e) o[e] = (f + e < DOUT) ? bo[f + e] : 0.f;
            *(vf4*)&bo_p[f] = o;
        }
    }
}

// ---------------------------------------------------------------------------
extern "C" void kernel_launch(void* const* d_in, const int* in_sizes, int n_in,
                              void* d_out, int out_size, void* d_ws, size_t ws_size,
                              hipStream_t stream)
{
    (void)in_sizes; (void)n_in; (void)out_size; (void)ws_size;
    const float* x     = (const float*)d_in[0];
    const float* rnd   = (const float*)d_in[1];
    const float* posi  = (const float*)d_in[2];
    const float* ln0_w = (const float*)d_in[3];
    const float* ln0_b = (const float*)d_in[4];
    const float* Wq    = (const float*)d_in[5];
    const float* bq    = (const float*)d_in[6];
    const float* Wk    = (const float*)d_in[7];
    const float* bk    = (const float*)d_in[8];
    const float* Wv    = (const float*)d_in[9];
    const float* bv    = (const float*)d_in[10];
    const float* Wfc   = (const float*)d_in[11];
    const float* bfc   = (const float*)d_in[12];
    const float* ln1_w = (const float*)d_in[13];
    const float* ln1_b = (const float*)d_in[14];
    const float* W1    = (const float*)d_in[15];
    const float* b1    = (const float*)d_in[16];
    const float* W2    = (const float*)d_in[17];
    const float* b2    = (const float*)d_in[18];
    const float* ln2_w = (const float*)d_in[19];
    const float* ln2_b = (const float*)d_in[20];
    const float* Wo    = (const float*)d_in[21];
    const float* bo    = (const float*)d_in[22];

    char* p = (char*)d_ws;
    size_t off = 0;
    auto take = [&](size_t bytes) {
        char* r = p + off;
        off += (bytes + 255) & ~(size_t)255;
        return r;
    };
    u16*   Wqk_b  = (u16*)take((size_t)NLAYER * 2048 * 1024 * 2);
    u16*   Wv_b   = (u16*)take((size_t)NLAYER * 1024 * 1024 * 2);
    u16*   Wfc_b  = (u16*)take((size_t)NLAYER * 1024 * 1024 * 2);
    u16*   W1_b   = (u16*)take((size_t)NLAYER * 4096 * 1024 * 2);
    u16*   W2_b   = (u16*)take((size_t)NLAYER * 4096 * 1024 * 2);
    u16*   Wo_b   = (u16*)take((size_t)DOUTP * DM * 2);
    float* bqk_p  = (float*)take(NLAYER * 2048 * 4);
    float* bo_p   = (float*)take(DOUTP * 4);
    u16*   enc_b  = (u16*)take((size_t)NTOK * DM * 2);
    char*  pool   = take((size_t)NTOK * DOUTP * 2);
    // lifetimes: qkv[0,33.5M) -> vt[33.5,50.3M) -> attn[50.3,67.1M);
    // fc[0,16.8M) (qkv dead); ff[0,67.1M) (qkv,vt,attn dead); ff2[67.1,83.9M); lgt[0,168M)
    u16*   qkv_b  = (u16*)(pool);
    u16*   vt_b   = (u16*)(pool + 33554432);
    u16*   attn_b = (u16*)(pool + 50331648);
    u16*   fc_b   = (u16*)(pool);
    u16*   ff_b   = (u16*)(pool);
    u16*   ff2_b  = (u16*)(pool + 67108864);
    u16*   lgt_b  = (u16*)(pool);

    const dim3 blk(256);
    prep_k<<<59410, blk, 0, stream>>>(Wq, Wk, Wv, Wfc, W1, W2, Wo, bq, bk, bo,
                                      Wqk_b, Wv_b, Wfc_b, W1_b, W2_b, Wo_b, bqk_p, bo_p);

    embed_k<<<NTOK, blk, 0, stream>>>(x, rnd, posi, ln0_w, ln0_b, enc_b);

    const size_t l2e = 4096 * 1024;
    for (int l = 0; l < NLAYER; ++l) {
        // QK: [8192,2048] = enc @ Wqk^T
        gemm2p<256, false, true><<<256, 512, 0, stream>>>(enc_b, Wqk_b + (size_t)l * 2097152,
                                                          bqk_p + l * 2048, qkv_b, 2048, 1024, 32, 8);
        // V: writes V^T (vt layout) directly via TRV epilogue
        gemm2p<128, false, true, true><<<256, 512, 0, stream>>>(enc_b, Wv_b + (size_t)l * 1048576,
                                                                bv + l * 1024, vt_b, 1024, 1024, 64, 4);
        attn_k<<<4096, blk, 0, stream>>>(qkv_b, qkv_b + 1024, vt_b, attn_b, 2048);
        gemm2p<128, false, true><<<256, 512, 0, stream>>>(attn_b, Wfc_b + (size_t)l * 1048576,
                                                          bfc + l * 1024, fc_b, 1024, 1024, 64, 4);
        add_ln_k<<<NTOK, blk, 0, stream>>>(fc_b, enc_b, ln1_w + l * 1024, ln1_b + l * 1024, enc_b);
        gemm2p<256, true, true><<<512, 512, 0, stream>>>(enc_b, W1_b + l * l2e, b1 + l * 4096,
                                                         ff_b, 4096, 1024, 32, 16);
        gemm2p<128, false, true><<<256, 512, 0, stream>>>(ff_b, W2_b + l * l2e, b2 + l * 1024,
                                                          ff2_b, 1024, 4096, 64, 4);
        add_ln_k<<<NTOK, blk, 0, stream>>>(ff2_b, enc_b, ln2_w + l * 1024, ln2_b + l * 1024, enc_b);
    }

    gemm2p<256, false, true><<<1280, 512, 0, stream>>>(enc_b, Wo_b, bo_p, lgt_b, DOUTP, 1024, 32, 40);
    logsm_k<<<NTOK, blk, 0, stream>>>(lgt_b, (float*)d_out);
}